// Round 5
// baseline (215.293 us; speedup 1.0000x reference)
//
#include <hip/hip_runtime.h>
#include <math.h>

#define H_IMG 1024
#define W_IMG 1280
#define NPIX (H_IMG * W_IMG)
#define NQUAD (NPIX / 4)          // 327680
#define RBLOCKS 256               // 1 block/CU: known-good L1/L2 regime (R2)
#define RTPB 256
#define NWAVES (RTPB / 64)        // 4
#define QPT (NQUAD / (RBLOCKS * RTPB))   // 5 quads (20 px) per thread, exact
#define NACC 28                    // 21 JtJ upper-tri + 6 JtR + 1 count
#define NORM_THR 0.93969262f       // float(cos(20 deg))
#define DIST_THR2 0.04f            // 0.2^2
#define DAMPING 1e-6
#define WB_MAX (3 * NPIX - 4)      // clamp so 16B gather stays in-bounds

// ws layout (doubles): [0..15] pose (f64)
//                      [16 .. 16+PART_DOUBLES) per-block partials (non-atomic)
//                      then one unsigned counter
#define PART_DOUBLES (RBLOCKS * NACC)

typedef __attribute__((ext_vector_type(4))) float f4;
// 4-byte-aligned float4: gathers at 12B stride are only dword-aligned.
// gfx950 supports dword-aligned dwordx4; worst case clang splits it (no worse
// than the 3 scalar loads we replace).
typedef float f4a __attribute__((ext_vector_type(4), aligned(4)));

// ---------------------------------------------------------------------------
__global__ __launch_bounds__(256) void icp_init(const float* __restrict__ pose_in,
                                                double* __restrict__ ws) {
    const int i = threadIdx.x;
    if (i < 16) ws[i] = (double)pose_in[i];
    for (int k = i; k < PART_DOUBLES; k += 256) ws[16 + k] = 0.0;
    if (i == 0) *(unsigned*)(ws + 16 + PART_DOUBLES) = 0u;
}

// ---------------------------------------------------------------------------
// 6x6 damped solve + exp_se3 + pose update, single thread, f64.
// tot[0..20] = JtJ upper tri, tot[21..26] = JtR, tot[27] = valid count.
__device__ void solve_and_update(const double* tot, double* pose_ws,
                                 float* out, int write_out) {
    double JtJ[6][6];
    {
        int k = 0;
        for (int i = 0; i < 6; ++i)
            for (int j = i; j < 6; ++j) { JtJ[i][j] = tot[k]; JtJ[j][i] = tot[k]; ++k; }
    }
    double tr = 0.0;
    for (int i = 0; i < 6; ++i) tr += JtJ[i][i];

    double A[6][7];
    for (int i = 0; i < 6; ++i) {
        for (int j = 0; j < 6; ++j) A[i][j] = JtJ[i][j] + (i == j ? tr * DAMPING : 0.0);
        A[i][6] = -tot[21 + i];
    }
    // Gaussian elimination w/ partial pivoting
    for (int c = 0; c < 6; ++c) {
        int piv = c; double mx = fabs(A[c][c]);
        for (int r = c + 1; r < 6; ++r) {
            double ar = fabs(A[r][c]);
            if (ar > mx) { mx = ar; piv = r; }
        }
        if (piv != c) for (int j = 0; j < 7; ++j) { double tmp = A[c][j]; A[c][j] = A[piv][j]; A[piv][j] = tmp; }
        double d = A[c][c]; if (d == 0.0) d = 1e-30;
        for (int r = c + 1; r < 6; ++r) {
            double f = A[r][c] / d;
            for (int j = c; j < 7; ++j) A[r][j] -= f * A[c][j];
        }
    }
    double xi[6];
    for (int i = 5; i >= 0; --i) {
        double s = A[i][6];
        for (int j = i + 1; j < 6; ++j) s -= A[i][j] * xi[j];
        double d = A[i][i]; if (d == 0.0) d = 1e-30;
        xi[i] = s / d;
    }

    const double w0 = xi[0], w1 = xi[1], w2 = xi[2];
    const double v0 = xi[3], v1 = xi[4], v2 = xi[5];
    double wh[3][3] = { {0.0, -w2, w1}, {w2, 0.0, -w0}, {-w1, w0, 0.0} };
    double wh2[3][3];
    for (int i = 0; i < 3; ++i)
        for (int j = 0; j < 3; ++j) {
            double s = 0.0;
            for (int k = 0; k < 3; ++k) s += wh[i][k] * wh[k][j];
            wh2[i][j] = s;
        }
    const double theta = sqrt(w0 * w0 + w1 * w1 + w2 * w2);
    const double eps = 1e-8;
    const double ts = (theta > eps) ? theta : eps;
    const double st = sin(ts), ct = cos(ts);
    const double cA = st / ts;
    const double cB = (1.0 - ct) / (ts * ts);
    const double cC = (ts - st) / (ts * ts * ts);
    const bool small = (theta <= eps);

    double ew[3][3], Jm[3][3];
    for (int i = 0; i < 3; ++i)
        for (int j = 0; j < 3; ++j) {
            double eye = (i == j) ? 1.0 : 0.0;
            ew[i][j] = small ? eye : (eye + cA * wh[i][j] + cB * wh2[i][j]);
            Jm[i][j] = small ? eye : (eye + cB * wh[i][j] + cC * wh2[i][j]);
        }
    double Jv[3];
    for (int i = 0; i < 3; ++i) Jv[i] = Jm[i][0] * v0 + Jm[i][1] * v1 + Jm[i][2] * v2;

    double T[16] = { ew[0][0], ew[0][1], ew[0][2], Jv[0],
                     ew[1][0], ew[1][1], ew[1][2], Jv[1],
                     ew[2][0], ew[2][1], ew[2][2], Jv[2],
                     0.0, 0.0, 0.0, 1.0 };
    double P[16];
    for (int i = 0; i < 16; ++i) P[i] = pose_ws[i];
    double NP[16];
    for (int i = 0; i < 4; ++i)
        for (int j = 0; j < 4; ++j) {
            double s = 0.0;
            for (int k = 0; k < 4; ++k) s += T[i * 4 + k] * P[k * 4 + j];
            NP[i * 4 + j] = s;
        }
    for (int i = 0; i < 16; ++i) pose_ws[i] = NP[i];

    if (write_out) {
        for (int i = 0; i < 16; ++i) out[i] = (float)NP[i];
        out[16] = (float)(tot[27] / (double)NPIX);
    }
}

// ---------------------------------------------------------------------------
// R2-proven structure; single new lever this round: vectorized dwordx4 gathers
// (vmem insts per quad 30 -> 14). launch_bounds(256,1): grid caps occupancy
// anyway; free VGPRs for in-flight gather batches.
__global__ __launch_bounds__(RTPB, 1) void icp_fused(
    const float* __restrict__ vert0, const float* __restrict__ vert1,
    const float* __restrict__ norm0, const float* __restrict__ norm1,
    const float* __restrict__ Kmat, double* __restrict__ ws,
    float* __restrict__ out, int write_out)
{
    const double* pose = ws;
    double* part = ws + 16;
    unsigned* counter = (unsigned*)(ws + 16 + PART_DOUBLES);

    const float R00 = (float)pose[0],  R01 = (float)pose[1],  R02 = (float)pose[2],  t0 = (float)pose[3];
    const float R10 = (float)pose[4],  R11 = (float)pose[5],  R12 = (float)pose[6],  t1 = (float)pose[7];
    const float R20 = (float)pose[8],  R21 = (float)pose[9],  R22 = (float)pose[10], t2 = (float)pose[11];
    const float fx = Kmat[0], cx = Kmat[2], fy = Kmat[4], cy = Kmat[5];

    float a[NACC];
#pragma unroll
    for (int k = 0; k < NACC; ++k) a[k] = 0.0f;

    const int tid0 = blockIdx.x * RTPB + threadIdx.x;
    const f4* v0q = (const f4*)vert0;
    const f4* n0q = (const f4*)norm0;

    // rolling 2-deep stream prefetch; non-temporal (touch-once, keep L2 for gathers)
    f4 cA0, cA1, cA2, cB0, cB1, cB2;
    {
        const int q = tid0;
        cA0 = __builtin_nontemporal_load(&v0q[q * 3 + 0]);
        cA1 = __builtin_nontemporal_load(&v0q[q * 3 + 1]);
        cA2 = __builtin_nontemporal_load(&v0q[q * 3 + 2]);
        cB0 = __builtin_nontemporal_load(&n0q[q * 3 + 0]);
        cB1 = __builtin_nontemporal_load(&n0q[q * 3 + 1]);
        cB2 = __builtin_nontemporal_load(&n0q[q * 3 + 2]);
    }

#pragma unroll
    for (int i = 0; i < QPT; ++i) {
        // ---- unpack current quad (4 px) ----
        const float vx[4] = {cA0.x, cA0.w, cA1.z, cA2.y};
        const float vy[4] = {cA0.y, cA1.x, cA1.w, cA2.z};
        const float vz[4] = {cA0.z, cA1.y, cA2.x, cA2.w};
        const float nx[4] = {cB0.x, cB0.w, cB1.z, cB2.y};
        const float ny[4] = {cB0.y, cB1.x, cB1.w, cB2.z};
        const float nz[4] = {cB0.z, cB1.y, cB2.x, cB2.w};

        // ---- phase A: project all 4 px, compute gather addresses ----
        float px[4], py[4], pz[4], nrx[4], nry[4], nrz[4];
        bool inview[4];
        int wb[4];
#pragma unroll
        for (int p = 0; p < 4; ++p) {
            px[p] = R00 * vx[p] + R01 * vy[p] + R02 * vz[p] + t0;
            py[p] = R10 * vx[p] + R11 * vy[p] + R12 * vz[p] + t1;
            pz[p] = R20 * vx[p] + R21 * vy[p] + R22 * vz[p] + t2;
            nrx[p] = R00 * nx[p] + R01 * ny[p] + R02 * nz[p];
            nry[p] = R10 * nx[p] + R11 * ny[p] + R12 * nz[p];
            nrz[p] = R20 * nx[p] + R21 * ny[p] + R22 * nz[p];
            const float u = px[p] / pz[p] * fx + cx;
            const float v = py[p] / pz[p] * fy + cy;
            inview[p] = (u > 0.0f) && (u < (float)(W_IMG - 1)) &&
                        (v > 0.0f) && (v < (float)(H_IMG - 1));
            const float uf = fminf(fmaxf(rintf(u), 0.0f), (float)(W_IMG - 1));
            const float vf = fminf(fmaxf(rintf(v), 0.0f), (float)(H_IMG - 1));
            int w = ((int)vf * W_IMG + (int)uf) * 3;
            wb[p] = (w > WB_MAX) ? WB_MAX : w;   // only clips the (always-!inview) last px
        }

        // ---- phase B: 8 vectorized gathers (1 dwordx4 per array per px) ----
        f4a gV[4], gN[4];
#pragma unroll
        for (int p = 0; p < 4; ++p) {
            gV[p] = *(const f4a*)(vert1 + wb[p]);
            gN[p] = *(const f4a*)(norm1 + wb[p]);
        }

        // ---- prefetch next quad's stream data (overlaps gather latency) ----
        f4 nA0, nA1, nA2, nB0, nB1, nB2;
        if (i + 1 < QPT) {
            const int q = tid0 + (i + 1) * (RBLOCKS * RTPB);
            nA0 = __builtin_nontemporal_load(&v0q[q * 3 + 0]);
            nA1 = __builtin_nontemporal_load(&v0q[q * 3 + 1]);
            nA2 = __builtin_nontemporal_load(&v0q[q * 3 + 2]);
            nB0 = __builtin_nontemporal_load(&n0q[q * 3 + 0]);
            nB1 = __builtin_nontemporal_load(&n0q[q * 3 + 1]);
            nB2 = __builtin_nontemporal_load(&n0q[q * 3 + 2]);
        }

        // ---- phase C: consume gathers, accumulate ----
#pragma unroll
        for (int p = 0; p < 4; ++p) {
            const float r1x = gV[p].x, r1y = gV[p].y, r1z = gV[p].z;
            const float m1x = gN[p].x, m1y = gN[p].y, m1z = gN[p].z;
            const float dx = px[p] - r1x, dy = py[p] - r1y, dz = pz[p] - r1z;
            const bool mask0 = vz[p] > 0.0f;
            const bool mask1 = r1z > 0.0f;
            const bool normal_ok =
                (nrx[p] * m1x + nry[p] * m1y + nrz[p] * m1z) > NORM_THR;
            const float d2 = dx * dx + dy * dy + dz * dz;
            const bool occ = (!inview[p]) || (d2 > DIST_THR2);
            const bool valid = (!occ) && mask0 && mask1 && normal_ok;

            if (valid) {
                const float res = m1x * dx + m1y * dy + m1z * dz;
                float J[6];
                J[0] = py[p] * m1z - pz[p] * m1y;
                J[1] = pz[p] * m1x - px[p] * m1z;
                J[2] = px[p] * m1y - py[p] * m1x;
                J[3] = m1x; J[4] = m1y; J[5] = m1z;
                int k = 0;
#pragma unroll
                for (int ii = 0; ii < 6; ++ii)
#pragma unroll
                    for (int jj = ii; jj < 6; ++jj) a[k++] += J[ii] * J[jj];
#pragma unroll
                for (int ii = 0; ii < 6; ++ii) a[21 + ii] += J[ii] * res;
                a[27] += 1.0f;
            }
        }

        if (i + 1 < QPT) {
            cA0 = nA0; cA1 = nA1; cA2 = nA2;
            cB0 = nB0; cB1 = nB1; cB2 = nB2;
        }
    }

    // ---- wave-64 tree reduction per component ----
#pragma unroll
    for (int k = 0; k < NACC; ++k) {
        float val = a[k];
        for (int off = 32; off > 0; off >>= 1) val += __shfl_down(val, off, 64);
        a[k] = val;
    }

    __shared__ float sh[NWAVES][NACC];
    const int lane = threadIdx.x & 63;
    const int wid  = threadIdx.x >> 6;
    if (lane == 0) {
#pragma unroll
        for (int k = 0; k < NACC; ++k) sh[wid][k] = a[k];
    }
    __syncthreads();

    const unsigned tid = threadIdx.x;
    // non-atomic per-block partial (agent-scope store for cross-XCD visibility)
    if (tid < NACC) {
        double s = 0.0;
#pragma unroll
        for (int w = 0; w < NWAVES; ++w) s += (double)sh[w][tid];
        __hip_atomic_store(&part[blockIdx.x * NACC + (int)tid], s,
                           __ATOMIC_RELAXED, __HIP_MEMORY_SCOPE_AGENT);
    }
    __syncthreads();

    __shared__ bool amLast;
    if (tid == 0) {
        __threadfence();   // release: partials visible before counter bump
        unsigned prev = atomicAdd(counter, 1u);
        amLast = (prev == gridDim.x - 1);
    }
    __syncthreads();

    if (amLast) {
        __threadfence();   // acquire side
        __shared__ double red[8][NACC];
        __shared__ double tot[NACC];
        const int k = (int)tid % NACC;   // component
        const int g = (int)tid / NACC;   // group
        if (tid < 8 * NACC) {
            double s = 0.0;
#pragma unroll
            for (int b = 0; b < RBLOCKS / 8; ++b) {
                const int blk = g + b * 8;
                s += __hip_atomic_load(&part[blk * NACC + k],
                                       __ATOMIC_RELAXED, __HIP_MEMORY_SCOPE_AGENT);
            }
            red[g][k] = s;
        }
        __syncthreads();
        if (tid < NACC) {
            double s = 0.0;
#pragma unroll
            for (int g2 = 0; g2 < 8; ++g2) s += red[g2][tid];
            tot[tid] = s;
        }
        __syncthreads();
        if (tid == 0) {
            solve_and_update(tot, ws, out, write_out);
            atomicExch(counter, 0u);   // reset for next dispatch
        }
    }
}

// ---------------------------------------------------------------------------
extern "C" void kernel_launch(void* const* d_in, const int* in_sizes, int n_in,
                              void* d_out, int out_size, void* d_ws, size_t ws_size,
                              hipStream_t stream) {
    const float* pose10 = (const float*)d_in[0];
    const float* vert0  = (const float*)d_in[1];
    const float* vert1  = (const float*)d_in[2];
    const float* norm0  = (const float*)d_in[3];
    const float* norm1  = (const float*)d_in[4];
    const float* Kmat   = (const float*)d_in[5];
    float* out = (float*)d_out;
    double* ws = (double*)d_ws;

    icp_init<<<1, 256, 0, stream>>>(pose10, ws);
    for (int it = 0; it < 3; ++it) {
        icp_fused<<<RBLOCKS, RTPB, 0, stream>>>(vert0, vert1, norm0, norm1,
                                                Kmat, ws, out, it == 2 ? 1 : 0);
    }
}

// Round 6
// 207.943 us; speedup vs baseline: 1.0354x; 1.0354x over previous
//
#include <hip/hip_runtime.h>
#include <math.h>

#define H_IMG 1024
#define W_IMG 1280
#define NPIX (H_IMG * W_IMG)
#define NQUAD (NPIX / 4)          // 327680
#define RBLOCKS 256               // 1 block/CU
#define RTPB 128                  // 2 waves/CU: per-CU vmem window ~24KB <= 32KB L1
#define NWAVES (RTPB / 64)        // 2
#define QPT (NQUAD / (RBLOCKS * RTPB))   // 10 quads (40 px) per thread, exact
#define NACC 28                    // 21 JtJ upper-tri + 6 JtR + 1 count
#define NORM_THR 0.93969262f       // float(cos(20 deg))
#define DIST_THR2 0.04f            // 0.2^2
#define DAMPING 1e-6

// ws layout (doubles): [0..15] pose (f64)
//                      [16 .. 16+PART_DOUBLES) per-block partials (non-atomic)
//                      then one unsigned counter
#define PART_DOUBLES (RBLOCKS * NACC)

typedef __attribute__((ext_vector_type(4))) float f4;

// ---------------------------------------------------------------------------
__global__ __launch_bounds__(256) void icp_init(const float* __restrict__ pose_in,
                                                double* __restrict__ ws) {
    const int i = threadIdx.x;
    if (i < 16) ws[i] = (double)pose_in[i];
    for (int k = i; k < PART_DOUBLES; k += 256) ws[16 + k] = 0.0;
    if (i == 0) *(unsigned*)(ws + 16 + PART_DOUBLES) = 0u;
}

// ---------------------------------------------------------------------------
// 6x6 damped solve + exp_se3 + pose update, single thread, f64.
// tot[0..20] = JtJ upper tri, tot[21..26] = JtR, tot[27] = valid count.
__device__ void solve_and_update(const double* tot, double* pose_ws,
                                 float* out, int write_out) {
    double JtJ[6][6];
    {
        int k = 0;
        for (int i = 0; i < 6; ++i)
            for (int j = i; j < 6; ++j) { JtJ[i][j] = tot[k]; JtJ[j][i] = tot[k]; ++k; }
    }
    double tr = 0.0;
    for (int i = 0; i < 6; ++i) tr += JtJ[i][i];

    double A[6][7];
    for (int i = 0; i < 6; ++i) {
        for (int j = 0; j < 6; ++j) A[i][j] = JtJ[i][j] + (i == j ? tr * DAMPING : 0.0);
        A[i][6] = -tot[21 + i];
    }
    // Gaussian elimination w/ partial pivoting
    for (int c = 0; c < 6; ++c) {
        int piv = c; double mx = fabs(A[c][c]);
        for (int r = c + 1; r < 6; ++r) {
            double ar = fabs(A[r][c]);
            if (ar > mx) { mx = ar; piv = r; }
        }
        if (piv != c) for (int j = 0; j < 7; ++j) { double tmp = A[c][j]; A[c][j] = A[piv][j]; A[piv][j] = tmp; }
        double d = A[c][c]; if (d == 0.0) d = 1e-30;
        for (int r = c + 1; r < 6; ++r) {
            double f = A[r][c] / d;
            for (int j = c; j < 7; ++j) A[r][j] -= f * A[c][j];
        }
    }
    double xi[6];
    for (int i = 5; i >= 0; --i) {
        double s = A[i][6];
        for (int j = i + 1; j < 6; ++j) s -= A[i][j] * xi[j];
        double d = A[i][i]; if (d == 0.0) d = 1e-30;
        xi[i] = s / d;
    }

    const double w0 = xi[0], w1 = xi[1], w2 = xi[2];
    const double v0 = xi[3], v1 = xi[4], v2 = xi[5];
    double wh[3][3] = { {0.0, -w2, w1}, {w2, 0.0, -w0}, {-w1, w0, 0.0} };
    double wh2[3][3];
    for (int i = 0; i < 3; ++i)
        for (int j = 0; j < 3; ++j) {
            double s = 0.0;
            for (int k = 0; k < 3; ++k) s += wh[i][k] * wh[k][j];
            wh2[i][j] = s;
        }
    const double theta = sqrt(w0 * w0 + w1 * w1 + w2 * w2);
    const double eps = 1e-8;
    const double ts = (theta > eps) ? theta : eps;
    const double st = sin(ts), ct = cos(ts);
    const double cA = st / ts;
    const double cB = (1.0 - ct) / (ts * ts);
    const double cC = (ts - st) / (ts * ts * ts);
    const bool small = (theta <= eps);

    double ew[3][3], Jm[3][3];
    for (int i = 0; i < 3; ++i)
        for (int j = 0; j < 3; ++j) {
            double eye = (i == j) ? 1.0 : 0.0;
            ew[i][j] = small ? eye : (eye + cA * wh[i][j] + cB * wh2[i][j]);
            Jm[i][j] = small ? eye : (eye + cB * wh[i][j] + cC * wh2[i][j]);
        }
    double Jv[3];
    for (int i = 0; i < 3; ++i) Jv[i] = Jm[i][0] * v0 + Jm[i][1] * v1 + Jm[i][2] * v2;

    double T[16] = { ew[0][0], ew[0][1], ew[0][2], Jv[0],
                     ew[1][0], ew[1][1], ew[1][2], Jv[1],
                     ew[2][0], ew[2][1], ew[2][2], Jv[2],
                     0.0, 0.0, 0.0, 1.0 };
    double P[16];
    for (int i = 0; i < 16; ++i) P[i] = pose_ws[i];
    double NP[16];
    for (int i = 0; i < 4; ++i)
        for (int j = 0; j < 4; ++j) {
            double s = 0.0;
            for (int k = 0; k < 4; ++k) s += T[i * 4 + k] * P[k * 4 + j];
            NP[i * 4 + j] = s;
        }
    for (int i = 0; i < 16; ++i) pose_ws[i] = NP[i];

    if (write_out) {
        for (int i = 0; i < 16; ++i) out[i] = (float)NP[i];
        out[16] = (float)(tot[27] / (double)NPIX);
    }
}

// ---------------------------------------------------------------------------
// R2 structure (41.6us proven: scalar gathers, plain stream loads, 2-deep
// prefetch, phase batching). Single change this round: 128 threads (2 waves/CU)
// x QPT=10 -> per-CU concurrent vmem window ~24KB fits the 32KB L1.
// launch_bounds(128,1): grid caps occupancy anyway; free VGPRs.
__global__ __launch_bounds__(RTPB, 1) void icp_fused(
    const float* __restrict__ vert0, const float* __restrict__ vert1,
    const float* __restrict__ norm0, const float* __restrict__ norm1,
    const float* __restrict__ Kmat, double* __restrict__ ws,
    float* __restrict__ out, int write_out)
{
    const double* pose = ws;
    double* part = ws + 16;
    unsigned* counter = (unsigned*)(ws + 16 + PART_DOUBLES);

    const float R00 = (float)pose[0],  R01 = (float)pose[1],  R02 = (float)pose[2],  t0 = (float)pose[3];
    const float R10 = (float)pose[4],  R11 = (float)pose[5],  R12 = (float)pose[6],  t1 = (float)pose[7];
    const float R20 = (float)pose[8],  R21 = (float)pose[9],  R22 = (float)pose[10], t2 = (float)pose[11];
    const float fx = Kmat[0], cx = Kmat[2], fy = Kmat[4], cy = Kmat[5];

    float a[NACC];
#pragma unroll
    for (int k = 0; k < NACC; ++k) a[k] = 0.0f;

    const int tid0 = blockIdx.x * RTPB + threadIdx.x;
    const f4* v0q = (const f4*)vert0;
    const f4* n0q = (const f4*)norm0;

    // rolling 2-deep stream prefetch
    f4 cA0, cA1, cA2, cB0, cB1, cB2;
    {
        const int q = tid0;
        cA0 = v0q[q * 3 + 0]; cA1 = v0q[q * 3 + 1]; cA2 = v0q[q * 3 + 2];
        cB0 = n0q[q * 3 + 0]; cB1 = n0q[q * 3 + 1]; cB2 = n0q[q * 3 + 2];
    }

#pragma unroll
    for (int i = 0; i < QPT; ++i) {
        // ---- unpack current quad (4 px) ----
        const float vx[4] = {cA0.x, cA0.w, cA1.z, cA2.y};
        const float vy[4] = {cA0.y, cA1.x, cA1.w, cA2.z};
        const float vz[4] = {cA0.z, cA1.y, cA2.x, cA2.w};
        const float nx[4] = {cB0.x, cB0.w, cB1.z, cB2.y};
        const float ny[4] = {cB0.y, cB1.x, cB1.w, cB2.z};
        const float nz[4] = {cB0.z, cB1.y, cB2.x, cB2.w};

        // ---- phase A: project all 4 px, compute gather addresses ----
        float px[4], py[4], pz[4], nrx[4], nry[4], nrz[4];
        bool inview[4];
        int wb[4];
#pragma unroll
        for (int p = 0; p < 4; ++p) {
            px[p] = R00 * vx[p] + R01 * vy[p] + R02 * vz[p] + t0;
            py[p] = R10 * vx[p] + R11 * vy[p] + R12 * vz[p] + t1;
            pz[p] = R20 * vx[p] + R21 * vy[p] + R22 * vz[p] + t2;
            nrx[p] = R00 * nx[p] + R01 * ny[p] + R02 * nz[p];
            nry[p] = R10 * nx[p] + R11 * ny[p] + R12 * nz[p];
            nrz[p] = R20 * nx[p] + R21 * ny[p] + R22 * nz[p];
            const float u = px[p] / pz[p] * fx + cx;
            const float v = py[p] / pz[p] * fy + cy;
            inview[p] = (u > 0.0f) && (u < (float)(W_IMG - 1)) &&
                        (v > 0.0f) && (v < (float)(H_IMG - 1));
            const float uf = fminf(fmaxf(rintf(u), 0.0f), (float)(W_IMG - 1));
            const float vf = fminf(fmaxf(rintf(v), 0.0f), (float)(H_IMG - 1));
            wb[p] = ((int)vf * W_IMG + (int)uf) * 3;
        }

        // ---- phase B: issue all 8 gather loads (4 px x 2 arrays, scalar) ----
        float r1x[4], r1y[4], r1z[4], m1x[4], m1y[4], m1z[4];
#pragma unroll
        for (int p = 0; p < 4; ++p) {
            r1x[p] = vert1[wb[p]]; r1y[p] = vert1[wb[p] + 1]; r1z[p] = vert1[wb[p] + 2];
            m1x[p] = norm1[wb[p]]; m1y[p] = norm1[wb[p] + 1]; m1z[p] = norm1[wb[p] + 2];
        }

        // ---- prefetch next quad's stream data (overlaps gather latency) ----
        f4 nA0, nA1, nA2, nB0, nB1, nB2;
        if (i + 1 < QPT) {
            const int q = tid0 + (i + 1) * (RBLOCKS * RTPB);
            nA0 = v0q[q * 3 + 0]; nA1 = v0q[q * 3 + 1]; nA2 = v0q[q * 3 + 2];
            nB0 = n0q[q * 3 + 0]; nB1 = n0q[q * 3 + 1]; nB2 = n0q[q * 3 + 2];
        }

        // ---- phase C: consume gathers, accumulate ----
#pragma unroll
        for (int p = 0; p < 4; ++p) {
            const float dx = px[p] - r1x[p], dy = py[p] - r1y[p], dz = pz[p] - r1z[p];
            const bool mask0 = vz[p] > 0.0f;
            const bool mask1 = r1z[p] > 0.0f;
            const bool normal_ok =
                (nrx[p] * m1x[p] + nry[p] * m1y[p] + nrz[p] * m1z[p]) > NORM_THR;
            const float d2 = dx * dx + dy * dy + dz * dz;
            const bool occ = (!inview[p]) || (d2 > DIST_THR2);
            const bool valid = (!occ) && mask0 && mask1 && normal_ok;

            if (valid) {
                const float res = m1x[p] * dx + m1y[p] * dy + m1z[p] * dz;
                float J[6];
                J[0] = py[p] * m1z[p] - pz[p] * m1y[p];
                J[1] = pz[p] * m1x[p] - px[p] * m1z[p];
                J[2] = px[p] * m1y[p] - py[p] * m1x[p];
                J[3] = m1x[p]; J[4] = m1y[p]; J[5] = m1z[p];
                int k = 0;
#pragma unroll
                for (int ii = 0; ii < 6; ++ii)
#pragma unroll
                    for (int jj = ii; jj < 6; ++jj) a[k++] += J[ii] * J[jj];
#pragma unroll
                for (int ii = 0; ii < 6; ++ii) a[21 + ii] += J[ii] * res;
                a[27] += 1.0f;
            }
        }

        if (i + 1 < QPT) {
            cA0 = nA0; cA1 = nA1; cA2 = nA2;
            cB0 = nB0; cB1 = nB1; cB2 = nB2;
        }
    }

    // ---- wave-64 tree reduction per component ----
#pragma unroll
    for (int k = 0; k < NACC; ++k) {
        float val = a[k];
        for (int off = 32; off > 0; off >>= 1) val += __shfl_down(val, off, 64);
        a[k] = val;
    }

    __shared__ float sh[NWAVES][NACC];
    const int lane = threadIdx.x & 63;
    const int wid  = threadIdx.x >> 6;
    if (lane == 0) {
#pragma unroll
        for (int k = 0; k < NACC; ++k) sh[wid][k] = a[k];
    }
    __syncthreads();

    const unsigned tid = threadIdx.x;
    // non-atomic per-block partial (agent-scope store for cross-XCD visibility)
    if (tid < NACC) {
        double s = 0.0;
#pragma unroll
        for (int w = 0; w < NWAVES; ++w) s += (double)sh[w][tid];
        __hip_atomic_store(&part[blockIdx.x * NACC + (int)tid], s,
                           __ATOMIC_RELAXED, __HIP_MEMORY_SCOPE_AGENT);
    }
    __syncthreads();

    __shared__ bool amLast;
    if (tid == 0) {
        __threadfence();   // release: partials visible before counter bump
        unsigned prev = atomicAdd(counter, 1u);
        amLast = (prev == gridDim.x - 1);
    }
    __syncthreads();

    if (amLast) {
        __threadfence();   // acquire side
        // 4 groups x 28 comps = 112 active threads (fits 128-thread block)
        __shared__ double red[4][NACC];
        __shared__ double tot[NACC];
        const int k = (int)tid % NACC;   // component
        const int g = (int)tid / NACC;   // group
        if (tid < 4 * NACC) {
            double s = 0.0;
#pragma unroll
            for (int b = 0; b < RBLOCKS / 4; ++b) {
                const int blk = g + b * 4;
                s += __hip_atomic_load(&part[blk * NACC + k],
                                       __ATOMIC_RELAXED, __HIP_MEMORY_SCOPE_AGENT);
            }
            red[g][k] = s;
        }
        __syncthreads();
        if (tid < NACC) {
            double s = 0.0;
#pragma unroll
            for (int g2 = 0; g2 < 4; ++g2) s += red[g2][tid];
            tot[tid] = s;
        }
        __syncthreads();
        if (tid == 0) {
            solve_and_update(tot, ws, out, write_out);
            atomicExch(counter, 0u);   // reset for next dispatch
        }
    }
}

// ---------------------------------------------------------------------------
extern "C" void kernel_launch(void* const* d_in, const int* in_sizes, int n_in,
                              void* d_out, int out_size, void* d_ws, size_t ws_size,
                              hipStream_t stream) {
    const float* pose10 = (const float*)d_in[0];
    const float* vert0  = (const float*)d_in[1];
    const float* vert1  = (const float*)d_in[2];
    const float* norm0  = (const float*)d_in[3];
    const float* norm1  = (const float*)d_in[4];
    const float* Kmat   = (const float*)d_in[5];
    float* out = (float*)d_out;
    double* ws = (double*)d_ws;

    icp_init<<<1, 256, 0, stream>>>(pose10, ws);
    for (int it = 0; it < 3; ++it) {
        icp_fused<<<RBLOCKS, RTPB, 0, stream>>>(vert0, vert1, norm0, norm1,
                                                Kmat, ws, out, it == 2 ? 1 : 0);
    }
}

// Round 8
// 189.841 us; speedup vs baseline: 1.1341x; 1.0953x over previous
//
#include <hip/hip_runtime.h>
#include <math.h>

#define H_IMG 1024
#define W_IMG 1280
#define NPIX (H_IMG * W_IMG)
#define NQUAD (NPIX / 4)          // 327680
#define RBLOCKS 256               // 1 block/CU (R2-proven geometry)
#define RTPB 256
#define NWAVES (RTPB / 64)        // 4
#define QPT (NQUAD / (RBLOCKS * RTPB))   // 5 quads (20 px) per thread, exact
#define NACC 28                    // 21 JtJ upper-tri + 6 JtR + 1 count
#define NORM_THR 0.93969262f       // float(cos(20 deg))
#define DIST_THR2 0.04f            // 0.2^2
#define DAMPING 1e-6

// ws layout: [0..15] pose (f64); [16 .. 16+PART_DOUBLES) per-block partials;
// one unsigned counter; then (packed path only) at byte offset PACK_BYTE_OFF
// the packed gather array: NPIX records x 32 B = {v.xyz n.x | n.yz 0 0}.
#define PART_DOUBLES (RBLOCKS * NACC)
#define PACK_BYTE_OFF 65536
#define PACK_BYTES ((size_t)NPIX * 32)
#define WS_NEEDED (PACK_BYTE_OFF + PACK_BYTES)   // ~40.1 MiB

typedef __attribute__((ext_vector_type(4))) float f4;

// ---------------------------------------------------------------------------
__global__ __launch_bounds__(256) void icp_init(const float* __restrict__ pose_in,
                                                double* __restrict__ ws) {
    const int i = threadIdx.x;
    if (i < 16) ws[i] = (double)pose_in[i];
    for (int k = i; k < PART_DOUBLES; k += 256) ws[16 + k] = 0.0;
    if (i == 0) *(unsigned*)(ws + 16 + PART_DOUBLES) = 0u;
}

// ---------------------------------------------------------------------------
// Packed path: repack vert1+norm1 into 32B AoS records + pose/counter init.
__global__ __launch_bounds__(RTPB) void icp_prep(
    const float* __restrict__ pose_in,
    const float* __restrict__ vert1, const float* __restrict__ norm1,
    double* __restrict__ ws)
{
    const int tid = threadIdx.x;
    if (blockIdx.x == 0) {
        if (tid < 16) ws[tid] = (double)pose_in[tid];
        if (tid == 16) *(unsigned*)(ws + 16 + PART_DOUBLES) = 0u;
    }

    f4* pk = (f4*)((char*)ws + PACK_BYTE_OFF);
    const f4* v1q = (const f4*)vert1;
    const f4* n1q = (const f4*)norm1;
    const int t0 = blockIdx.x * RTPB + tid;

#pragma unroll
    for (int i = 0; i < QPT; ++i) {
        const int q = t0 + i * (RBLOCKS * RTPB);
        const f4 A0 = v1q[q * 3 + 0], A1 = v1q[q * 3 + 1], A2 = v1q[q * 3 + 2];
        const f4 B0 = n1q[q * 3 + 0], B1 = n1q[q * 3 + 1], B2 = n1q[q * 3 + 2];
        const float vx[4] = {A0.x, A0.w, A1.z, A2.y};
        const float vy[4] = {A0.y, A1.x, A1.w, A2.z};
        const float vz[4] = {A0.z, A1.y, A2.x, A2.w};
        const float nx[4] = {B0.x, B0.w, B1.z, B2.y};
        const float ny[4] = {B0.y, B1.x, B1.w, B2.z};
        const float nz[4] = {B0.z, B1.y, B2.x, B2.w};
#pragma unroll
        for (int p = 0; p < 4; ++p) {
            const int r = q * 4 + p;
            f4 g0 = {vx[p], vy[p], vz[p], nx[p]};
            f4 g1 = {ny[p], nz[p], 0.0f, 0.0f};
            pk[r * 2 + 0] = g0;      // lane-contiguous 128B runs: coalesced
            pk[r * 2 + 1] = g1;
        }
    }
}

// ---------------------------------------------------------------------------
// 6x6 damped solve + exp_se3 + pose update, single thread, f64.
__device__ void solve_and_update(const double* tot, double* pose_ws,
                                 float* out, int write_out) {
    double JtJ[6][6];
    {
        int k = 0;
        for (int i = 0; i < 6; ++i)
            for (int j = i; j < 6; ++j) { JtJ[i][j] = tot[k]; JtJ[j][i] = tot[k]; ++k; }
    }
    double tr = 0.0;
    for (int i = 0; i < 6; ++i) tr += JtJ[i][i];

    double A[6][7];
    for (int i = 0; i < 6; ++i) {
        for (int j = 0; j < 6; ++j) A[i][j] = JtJ[i][j] + (i == j ? tr * DAMPING : 0.0);
        A[i][6] = -tot[21 + i];
    }
    for (int c = 0; c < 6; ++c) {
        int piv = c; double mx = fabs(A[c][c]);
        for (int r = c + 1; r < 6; ++r) {
            double ar = fabs(A[r][c]);
            if (ar > mx) { mx = ar; piv = r; }
        }
        if (piv != c) for (int j = 0; j < 7; ++j) { double tmp = A[c][j]; A[c][j] = A[piv][j]; A[piv][j] = tmp; }
        double d = A[c][c]; if (d == 0.0) d = 1e-30;
        for (int r = c + 1; r < 6; ++r) {
            double f = A[r][c] / d;
            for (int j = c; j < 7; ++j) A[r][j] -= f * A[c][j];
        }
    }
    double xi[6];
    for (int i = 5; i >= 0; --i) {
        double s = A[i][6];
        for (int j = i + 1; j < 6; ++j) s -= A[i][j] * xi[j];
        double d = A[i][i]; if (d == 0.0) d = 1e-30;
        xi[i] = s / d;
    }

    const double w0 = xi[0], w1 = xi[1], w2 = xi[2];
    const double v0 = xi[3], v1 = xi[4], v2 = xi[5];
    double wh[3][3] = { {0.0, -w2, w1}, {w2, 0.0, -w0}, {-w1, w0, 0.0} };
    double wh2[3][3];
    for (int i = 0; i < 3; ++i)
        for (int j = 0; j < 3; ++j) {
            double s = 0.0;
            for (int k = 0; k < 3; ++k) s += wh[i][k] * wh[k][j];
            wh2[i][j] = s;
        }
    const double theta = sqrt(w0 * w0 + w1 * w1 + w2 * w2);
    const double eps = 1e-8;
    const double ts = (theta > eps) ? theta : eps;
    const double st = sin(ts), ct = cos(ts);
    const double cA = st / ts;
    const double cB = (1.0 - ct) / (ts * ts);
    const double cC = (ts - st) / (ts * ts * ts);
    const bool small = (theta <= eps);

    double ew[3][3], Jm[3][3];
    for (int i = 0; i < 3; ++i)
        for (int j = 0; j < 3; ++j) {
            double eye = (i == j) ? 1.0 : 0.0;
            ew[i][j] = small ? eye : (eye + cA * wh[i][j] + cB * wh2[i][j]);
            Jm[i][j] = small ? eye : (eye + cB * wh[i][j] + cC * wh2[i][j]);
        }
    double Jv[3];
    for (int i = 0; i < 3; ++i) Jv[i] = Jm[i][0] * v0 + Jm[i][1] * v1 + Jm[i][2] * v2;

    double T[16] = { ew[0][0], ew[0][1], ew[0][2], Jv[0],
                     ew[1][0], ew[1][1], ew[1][2], Jv[1],
                     ew[2][0], ew[2][1], ew[2][2], Jv[2],
                     0.0, 0.0, 0.0, 1.0 };
    double P[16];
    for (int i = 0; i < 16; ++i) P[i] = pose_ws[i];
    double NP[16];
    for (int i = 0; i < 4; ++i)
        for (int j = 0; j < 4; ++j) {
            double s = 0.0;
            for (int k = 0; k < 4; ++k) s += T[i * 4 + k] * P[k * 4 + j];
            NP[i * 4 + j] = s;
        }
    for (int i = 0; i < 16; ++i) pose_ws[i] = NP[i];

    if (write_out) {
        for (int i = 0; i < 16; ++i) out[i] = (float)NP[i];
        out[16] = (float)(tot[27] / (double)NPIX);
    }
}

// ---------------------------------------------------------------------------
// Shared epilogue: wave reduce -> per-block partial -> amLast reduce+solve.
__device__ __forceinline__ void reduce_and_finish(
    float a[NACC], double* ws, float* out, int write_out)
{
    double* part = ws + 16;
    unsigned* counter = (unsigned*)(ws + 16 + PART_DOUBLES);

#pragma unroll
    for (int k = 0; k < NACC; ++k) {
        float val = a[k];
        for (int off = 32; off > 0; off >>= 1) val += __shfl_down(val, off, 64);
        a[k] = val;
    }

    __shared__ float sh[NWAVES][NACC];
    const int lane = threadIdx.x & 63;
    const int wid  = threadIdx.x >> 6;
    if (lane == 0) {
#pragma unroll
        for (int k = 0; k < NACC; ++k) sh[wid][k] = a[k];
    }
    __syncthreads();

    const unsigned tid = threadIdx.x;
    if (tid < NACC) {
        double s = 0.0;
#pragma unroll
        for (int w = 0; w < NWAVES; ++w) s += (double)sh[w][tid];
        __hip_atomic_store(&part[blockIdx.x * NACC + (int)tid], s,
                           __ATOMIC_RELAXED, __HIP_MEMORY_SCOPE_AGENT);
    }
    __syncthreads();

    __shared__ bool amLast;
    if (tid == 0) {
        __threadfence();
        unsigned prev = atomicAdd(counter, 1u);
        amLast = (prev == gridDim.x - 1);
    }
    __syncthreads();

    if (amLast) {
        __threadfence();
        __shared__ double red[8][NACC];
        __shared__ double tot[NACC];
        const int k = (int)tid % NACC;
        const int g = (int)tid / NACC;
        if (tid < 8 * NACC) {
            double s = 0.0;
#pragma unroll
            for (int b = 0; b < RBLOCKS / 8; ++b) {
                const int blk = g + b * 8;
                s += __hip_atomic_load(&part[blk * NACC + k],
                                       __ATOMIC_RELAXED, __HIP_MEMORY_SCOPE_AGENT);
            }
            red[g][k] = s;
        }
        __syncthreads();
        if (tid < NACC) {
            double s = 0.0;
#pragma unroll
            for (int g2 = 0; g2 < 8; ++g2) s += red[g2][tid];
            tot[tid] = s;
        }
        __syncthreads();
        if (tid == 0) {
            solve_and_update(tot, ws, out, write_out);
            atomicExch(counter, 0u);
        }
    }
}

// ---------------------------------------------------------------------------
// PACKED-path kernel: 2 aligned dwordx4 gathers per px from 32B records.
__global__ __launch_bounds__(RTPB, 1) void icp_fused_pk(
    const float* __restrict__ vert0, const float* __restrict__ norm0,
    const float* __restrict__ Kmat, double* __restrict__ ws,
    float* __restrict__ out, int write_out)
{
    const double* pose = ws;
    const f4* pk = (const f4*)((const char*)ws + PACK_BYTE_OFF);

    const float R00 = (float)pose[0],  R01 = (float)pose[1],  R02 = (float)pose[2],  t0 = (float)pose[3];
    const float R10 = (float)pose[4],  R11 = (float)pose[5],  R12 = (float)pose[6],  t1 = (float)pose[7];
    const float R20 = (float)pose[8],  R21 = (float)pose[9],  R22 = (float)pose[10], t2 = (float)pose[11];
    const float fx = Kmat[0], cx = Kmat[2], fy = Kmat[4], cy = Kmat[5];

    float a[NACC];
#pragma unroll
    for (int k = 0; k < NACC; ++k) a[k] = 0.0f;

    // XCD-chunked swizzle (bijective: 256 = 8 XCDs x 32) for DATA assignment.
    const int sbid = (blockIdx.x & 7) * 32 + (blockIdx.x >> 3);
    const int tid0 = sbid * RTPB + threadIdx.x;
    const f4* v0q = (const f4*)vert0;
    const f4* n0q = (const f4*)norm0;

    f4 cA0, cA1, cA2, cB0, cB1, cB2;
    {
        const int q = tid0;
        cA0 = v0q[q * 3 + 0]; cA1 = v0q[q * 3 + 1]; cA2 = v0q[q * 3 + 2];
        cB0 = n0q[q * 3 + 0]; cB1 = n0q[q * 3 + 1]; cB2 = n0q[q * 3 + 2];
    }

#pragma unroll
    for (int i = 0; i < QPT; ++i) {
        const float vx[4] = {cA0.x, cA0.w, cA1.z, cA2.y};
        const float vy[4] = {cA0.y, cA1.x, cA1.w, cA2.z};
        const float vz[4] = {cA0.z, cA1.y, cA2.x, cA2.w};
        const float nx[4] = {cB0.x, cB0.w, cB1.z, cB2.y};
        const float ny[4] = {cB0.y, cB1.x, cB1.w, cB2.z};
        const float nz[4] = {cB0.z, cB1.y, cB2.x, cB2.w};

        float px[4], py[4], pz[4], nrx[4], nry[4], nrz[4];
        bool inview[4];
        int ridx[4];
#pragma unroll
        for (int p = 0; p < 4; ++p) {
            px[p] = R00 * vx[p] + R01 * vy[p] + R02 * vz[p] + t0;
            py[p] = R10 * vx[p] + R11 * vy[p] + R12 * vz[p] + t1;
            pz[p] = R20 * vx[p] + R21 * vy[p] + R22 * vz[p] + t2;
            nrx[p] = R00 * nx[p] + R01 * ny[p] + R02 * nz[p];
            nry[p] = R10 * nx[p] + R11 * ny[p] + R12 * nz[p];
            nrz[p] = R20 * nx[p] + R21 * ny[p] + R22 * nz[p];
            const float u = px[p] / pz[p] * fx + cx;
            const float v = py[p] / pz[p] * fy + cy;
            inview[p] = (u > 0.0f) && (u < (float)(W_IMG - 1)) &&
                        (v > 0.0f) && (v < (float)(H_IMG - 1));
            const float uf = fminf(fmaxf(rintf(u), 0.0f), (float)(W_IMG - 1));
            const float vf = fminf(fmaxf(rintf(v), 0.0f), (float)(H_IMG - 1));
            ridx[p] = (int)vf * W_IMG + (int)uf;
        }

        f4 g0[4], g1[4];
#pragma unroll
        for (int p = 0; p < 4; ++p) {
            g0[p] = pk[ridx[p] * 2 + 0];
            g1[p] = pk[ridx[p] * 2 + 1];
        }

        f4 nA0, nA1, nA2, nB0, nB1, nB2;
        if (i + 1 < QPT) {
            const int q = tid0 + (i + 1) * (RBLOCKS * RTPB);
            nA0 = v0q[q * 3 + 0]; nA1 = v0q[q * 3 + 1]; nA2 = v0q[q * 3 + 2];
            nB0 = n0q[q * 3 + 0]; nB1 = n0q[q * 3 + 1]; nB2 = n0q[q * 3 + 2];
        }

#pragma unroll
        for (int p = 0; p < 4; ++p) {
            const float r1x = g0[p].x, r1y = g0[p].y, r1z = g0[p].z;
            const float m1x = g0[p].w, m1y = g1[p].x, m1z = g1[p].y;
            const float dx = px[p] - r1x, dy = py[p] - r1y, dz = pz[p] - r1z;
            const bool mask0 = vz[p] > 0.0f;
            const bool mask1 = r1z > 0.0f;
            const bool normal_ok =
                (nrx[p] * m1x + nry[p] * m1y + nrz[p] * m1z) > NORM_THR;
            const float d2 = dx * dx + dy * dy + dz * dz;
            const bool occ = (!inview[p]) || (d2 > DIST_THR2);
            const bool valid = (!occ) && mask0 && mask1 && normal_ok;

            if (valid) {
                const float res = m1x * dx + m1y * dy + m1z * dz;
                float J[6];
                J[0] = py[p] * m1z - pz[p] * m1y;
                J[1] = pz[p] * m1x - px[p] * m1z;
                J[2] = px[p] * m1y - py[p] * m1x;
                J[3] = m1x; J[4] = m1y; J[5] = m1z;
                int k = 0;
#pragma unroll
                for (int ii = 0; ii < 6; ++ii)
#pragma unroll
                    for (int jj = ii; jj < 6; ++jj) a[k++] += J[ii] * J[jj];
#pragma unroll
                for (int ii = 0; ii < 6; ++ii) a[21 + ii] += J[ii] * res;
                a[27] += 1.0f;
            }
        }

        if (i + 1 < QPT) {
            cA0 = nA0; cA1 = nA1; cA2 = nA2;
            cB0 = nB0; cB1 = nB1; cB2 = nB2;
        }
    }

    reduce_and_finish(a, ws, out, write_out);
}

// ---------------------------------------------------------------------------
// FALLBACK kernel (small ws): R2-proven direct scalar gathers + XCD swizzle.
__global__ __launch_bounds__(RTPB, 1) void icp_fused_dg(
    const float* __restrict__ vert0, const float* __restrict__ vert1,
    const float* __restrict__ norm0, const float* __restrict__ norm1,
    const float* __restrict__ Kmat, double* __restrict__ ws,
    float* __restrict__ out, int write_out)
{
    const double* pose = ws;

    const float R00 = (float)pose[0],  R01 = (float)pose[1],  R02 = (float)pose[2],  t0 = (float)pose[3];
    const float R10 = (float)pose[4],  R11 = (float)pose[5],  R12 = (float)pose[6],  t1 = (float)pose[7];
    const float R20 = (float)pose[8],  R21 = (float)pose[9],  R22 = (float)pose[10], t2 = (float)pose[11];
    const float fx = Kmat[0], cx = Kmat[2], fy = Kmat[4], cy = Kmat[5];

    float a[NACC];
#pragma unroll
    for (int k = 0; k < NACC; ++k) a[k] = 0.0f;

    const int sbid = (blockIdx.x & 7) * 32 + (blockIdx.x >> 3);
    const int tid0 = sbid * RTPB + threadIdx.x;
    const f4* v0q = (const f4*)vert0;
    const f4* n0q = (const f4*)norm0;

    f4 cA0, cA1, cA2, cB0, cB1, cB2;
    {
        const int q = tid0;
        cA0 = v0q[q * 3 + 0]; cA1 = v0q[q * 3 + 1]; cA2 = v0q[q * 3 + 2];
        cB0 = n0q[q * 3 + 0]; cB1 = n0q[q * 3 + 1]; cB2 = n0q[q * 3 + 2];
    }

#pragma unroll
    for (int i = 0; i < QPT; ++i) {
        const float vx[4] = {cA0.x, cA0.w, cA1.z, cA2.y};
        const float vy[4] = {cA0.y, cA1.x, cA1.w, cA2.z};
        const float vz[4] = {cA0.z, cA1.y, cA2.x, cA2.w};
        const float nx[4] = {cB0.x, cB0.w, cB1.z, cB2.y};
        const float ny[4] = {cB0.y, cB1.x, cB1.w, cB2.z};
        const float nz[4] = {cB0.z, cB1.y, cB2.x, cB2.w};

        float px[4], py[4], pz[4], nrx[4], nry[4], nrz[4];
        bool inview[4];
        int wb[4];
#pragma unroll
        for (int p = 0; p < 4; ++p) {
            px[p] = R00 * vx[p] + R01 * vy[p] + R02 * vz[p] + t0;
            py[p] = R10 * vx[p] + R11 * vy[p] + R12 * vz[p] + t1;
            pz[p] = R20 * vx[p] + R21 * vy[p] + R22 * vz[p] + t2;
            nrx[p] = R00 * nx[p] + R01 * ny[p] + R02 * nz[p];
            nry[p] = R10 * nx[p] + R11 * ny[p] + R12 * nz[p];
            nrz[p] = R20 * nx[p] + R21 * ny[p] + R22 * nz[p];
            const float u = px[p] / pz[p] * fx + cx;
            const float v = py[p] / pz[p] * fy + cy;
            inview[p] = (u > 0.0f) && (u < (float)(W_IMG - 1)) &&
                        (v > 0.0f) && (v < (float)(H_IMG - 1));
            const float uf = fminf(fmaxf(rintf(u), 0.0f), (float)(W_IMG - 1));
            const float vf = fminf(fmaxf(rintf(v), 0.0f), (float)(H_IMG - 1));
            wb[p] = ((int)vf * W_IMG + (int)uf) * 3;
        }

        float r1x[4], r1y[4], r1z[4], m1x[4], m1y[4], m1z[4];
#pragma unroll
        for (int p = 0; p < 4; ++p) {
            r1x[p] = vert1[wb[p]]; r1y[p] = vert1[wb[p] + 1]; r1z[p] = vert1[wb[p] + 2];
            m1x[p] = norm1[wb[p]]; m1y[p] = norm1[wb[p] + 1]; m1z[p] = norm1[wb[p] + 2];
        }

        f4 nA0, nA1, nA2, nB0, nB1, nB2;
        if (i + 1 < QPT) {
            const int q = tid0 + (i + 1) * (RBLOCKS * RTPB);
            nA0 = v0q[q * 3 + 0]; nA1 = v0q[q * 3 + 1]; nA2 = v0q[q * 3 + 2];
            nB0 = n0q[q * 3 + 0]; nB1 = n0q[q * 3 + 1]; nB2 = n0q[q * 3 + 2];
        }

#pragma unroll
        for (int p = 0; p < 4; ++p) {
            const float dx = px[p] - r1x[p], dy = py[p] - r1y[p], dz = pz[p] - r1z[p];
            const bool mask0 = vz[p] > 0.0f;
            const bool mask1 = r1z[p] > 0.0f;
            const bool normal_ok =
                (nrx[p] * m1x[p] + nry[p] * m1y[p] + nrz[p] * m1z[p]) > NORM_THR;
            const float d2 = dx * dx + dy * dy + dz * dz;
            const bool occ = (!inview[p]) || (d2 > DIST_THR2);
            const bool valid = (!occ) && mask0 && mask1 && normal_ok;

            if (valid) {
                const float res = m1x[p] * dx + m1y[p] * dy + m1z[p] * dz;
                float J[6];
                J[0] = py[p] * m1z[p] - pz[p] * m1y[p];
                J[1] = pz[p] * m1x[p] - px[p] * m1z[p];
                J[2] = px[p] * m1y[p] - py[p] * m1x[p];
                J[3] = m1x[p]; J[4] = m1y[p]; J[5] = m1z[p];
                int k = 0;
#pragma unroll
                for (int ii = 0; ii < 6; ++ii)
#pragma unroll
                    for (int jj = ii; jj < 6; ++jj) a[k++] += J[ii] * J[jj];
#pragma unroll
                for (int ii = 0; ii < 6; ++ii) a[21 + ii] += J[ii] * res;
                a[27] += 1.0f;
            }
        }

        if (i + 1 < QPT) {
            cA0 = nA0; cA1 = nA1; cA2 = nA2;
            cB0 = nB0; cB1 = nB1; cB2 = nB2;
        }
    }

    reduce_and_finish(a, ws, out, write_out);
}

// ---------------------------------------------------------------------------
extern "C" void kernel_launch(void* const* d_in, const int* in_sizes, int n_in,
                              void* d_out, int out_size, void* d_ws, size_t ws_size,
                              hipStream_t stream) {
    const float* pose10 = (const float*)d_in[0];
    const float* vert0  = (const float*)d_in[1];
    const float* vert1  = (const float*)d_in[2];
    const float* norm0  = (const float*)d_in[3];
    const float* norm1  = (const float*)d_in[4];
    const float* Kmat   = (const float*)d_in[5];
    float* out = (float*)d_out;
    double* ws = (double*)d_ws;

    if (ws_size >= WS_NEEDED) {
        // Packed path: repack once, then 3 iterations of dwordx4-gather kernel.
        icp_prep<<<RBLOCKS, RTPB, 0, stream>>>(pose10, vert1, norm1, ws);
        for (int it = 0; it < 3; ++it) {
            icp_fused_pk<<<RBLOCKS, RTPB, 0, stream>>>(vert0, norm0, Kmat, ws,
                                                       out, it == 2 ? 1 : 0);
        }
    } else {
        // Fallback: proven direct-gather kernel (+ XCD swizzle), tiny ws use.
        icp_init<<<1, 256, 0, stream>>>(pose10, ws);
        for (int it = 0; it < 3; ++it) {
            icp_fused_dg<<<RBLOCKS, RTPB, 0, stream>>>(vert0, vert1, norm0, norm1,
                                                       Kmat, ws, out, it == 2 ? 1 : 0);
        }
    }
}

// Round 9
// 176.034 us; speedup vs baseline: 1.2230x; 1.0784x over previous
//
#include <hip/hip_runtime.h>
#include <math.h>

#define H_IMG 1024
#define W_IMG 1280
#define NPIX (H_IMG * W_IMG)
#define RBLOCKS 256               // 1 block/CU
#define RTPB 256
#define NWAVES (RTPB / 64)        // 4
#define STRIDE (RBLOCKS * RTPB)   // 65536 threads total
#define PPT (NPIX / STRIDE)       // 20 pixels per thread, exact
#define GROUPS (PPT / 4)          // 5 groups of 4 pixel-slots
#define NACC 28                   // 21 JtJ upper-tri + 6 JtR + 1 count
#define NORM_THR 0.93969262f      // float(cos(20 deg))
#define DIST_THR2 0.04f           // 0.2^2
#define DAMPING 1e-6

// ws layout: [0..15] pose (f64); [16 .. 16+PART_DOUBLES) per-block partials;
// then one unsigned counter. (<60 KB total — no large ws use this round.)
#define PART_DOUBLES (RBLOCKS * NACC)

// ---------------------------------------------------------------------------
// Tiny init: only the completion counter needs a defined start value.
// (pose ws[0..15] is written by iter0's solve; partials are overwritten.)
__global__ void icp_init0(double* __restrict__ ws) {
    if (threadIdx.x == 0) *(unsigned*)(ws + 16 + PART_DOUBLES) = 0u;
}

// ---------------------------------------------------------------------------
// 6x6 damped solve + exp_se3 + pose update, single thread, f64.
// it==0 chains off pose_in (float); else off pose_ws (f64).
__device__ void solve_and_update(const double* tot, double* pose_ws,
                                 const float* pose_in, int it,
                                 float* out, int write_out) {
    double JtJ[6][6];
    {
        int k = 0;
        for (int i = 0; i < 6; ++i)
            for (int j = i; j < 6; ++j) { JtJ[i][j] = tot[k]; JtJ[j][i] = tot[k]; ++k; }
    }
    double tr = 0.0;
    for (int i = 0; i < 6; ++i) tr += JtJ[i][i];

    double A[6][7];
    for (int i = 0; i < 6; ++i) {
        for (int j = 0; j < 6; ++j) A[i][j] = JtJ[i][j] + (i == j ? tr * DAMPING : 0.0);
        A[i][6] = -tot[21 + i];
    }
    for (int c = 0; c < 6; ++c) {
        int piv = c; double mx = fabs(A[c][c]);
        for (int r = c + 1; r < 6; ++r) {
            double ar = fabs(A[r][c]);
            if (ar > mx) { mx = ar; piv = r; }
        }
        if (piv != c) for (int j = 0; j < 7; ++j) { double tmp = A[c][j]; A[c][j] = A[piv][j]; A[piv][j] = tmp; }
        double d = A[c][c]; if (d == 0.0) d = 1e-30;
        for (int r = c + 1; r < 6; ++r) {
            double f = A[r][c] / d;
            for (int j = c; j < 7; ++j) A[r][j] -= f * A[c][j];
        }
    }
    double xi[6];
    for (int i = 5; i >= 0; --i) {
        double s = A[i][6];
        for (int j = i + 1; j < 6; ++j) s -= A[i][j] * xi[j];
        double d = A[i][i]; if (d == 0.0) d = 1e-30;
        xi[i] = s / d;
    }

    const double w0 = xi[0], w1 = xi[1], w2 = xi[2];
    const double v0 = xi[3], v1 = xi[4], v2 = xi[5];
    double wh[3][3] = { {0.0, -w2, w1}, {w2, 0.0, -w0}, {-w1, w0, 0.0} };
    double wh2[3][3];
    for (int i = 0; i < 3; ++i)
        for (int j = 0; j < 3; ++j) {
            double s = 0.0;
            for (int k = 0; k < 3; ++k) s += wh[i][k] * wh[k][j];
            wh2[i][j] = s;
        }
    const double theta = sqrt(w0 * w0 + w1 * w1 + w2 * w2);
    const double eps = 1e-8;
    const double ts = (theta > eps) ? theta : eps;
    const double st = sin(ts), ct = cos(ts);
    const double cA = st / ts;
    const double cB = (1.0 - ct) / (ts * ts);
    const double cC = (ts - st) / (ts * ts * ts);
    const bool small = (theta <= eps);

    double ew[3][3], Jm[3][3];
    for (int i = 0; i < 3; ++i)
        for (int j = 0; j < 3; ++j) {
            double eye = (i == j) ? 1.0 : 0.0;
            ew[i][j] = small ? eye : (eye + cA * wh[i][j] + cB * wh2[i][j]);
            Jm[i][j] = small ? eye : (eye + cB * wh[i][j] + cC * wh2[i][j]);
        }
    double Jv[3];
    for (int i = 0; i < 3; ++i) Jv[i] = Jm[i][0] * v0 + Jm[i][1] * v1 + Jm[i][2] * v2;

    double T[16] = { ew[0][0], ew[0][1], ew[0][2], Jv[0],
                     ew[1][0], ew[1][1], ew[1][2], Jv[1],
                     ew[2][0], ew[2][1], ew[2][2], Jv[2],
                     0.0, 0.0, 0.0, 1.0 };
    double P[16];
    for (int i = 0; i < 16; ++i) P[i] = (it == 0) ? (double)pose_in[i] : pose_ws[i];
    double NP[16];
    for (int i = 0; i < 4; ++i)
        for (int j = 0; j < 4; ++j) {
            double s = 0.0;
            for (int k = 0; k < 4; ++k) s += T[i * 4 + k] * P[k * 4 + j];
            NP[i * 4 + j] = s;
        }
    for (int i = 0; i < 16; ++i) pose_ws[i] = NP[i];

    if (write_out) {
        for (int i = 0; i < 16; ++i) out[i] = (float)NP[i];
        out[16] = (float)(tot[27] / (double)NPIX);
    }
}

// ---------------------------------------------------------------------------
// Shared epilogue: wave reduce -> per-block partial -> amLast reduce+solve.
__device__ __forceinline__ void reduce_and_finish(
    float a[NACC], double* ws, const float* pose_in, int it,
    float* out, int write_out)
{
    double* part = ws + 16;
    unsigned* counter = (unsigned*)(ws + 16 + PART_DOUBLES);

#pragma unroll
    for (int k = 0; k < NACC; ++k) {
        float val = a[k];
        for (int off = 32; off > 0; off >>= 1) val += __shfl_down(val, off, 64);
        a[k] = val;
    }

    __shared__ float sh[NWAVES][NACC];
    const int lane = threadIdx.x & 63;
    const int wid  = threadIdx.x >> 6;
    if (lane == 0) {
#pragma unroll
        for (int k = 0; k < NACC; ++k) sh[wid][k] = a[k];
    }
    __syncthreads();

    const unsigned tid = threadIdx.x;
    if (tid < NACC) {
        double s = 0.0;
#pragma unroll
        for (int w = 0; w < NWAVES; ++w) s += (double)sh[w][tid];
        __hip_atomic_store(&part[blockIdx.x * NACC + (int)tid], s,
                           __ATOMIC_RELAXED, __HIP_MEMORY_SCOPE_AGENT);
    }
    __syncthreads();

    __shared__ bool amLast;
    if (tid == 0) {
        __threadfence();
        unsigned prev = atomicAdd(counter, 1u);
        amLast = (prev == gridDim.x - 1);
    }
    __syncthreads();

    if (amLast) {
        __threadfence();
        __shared__ double red[8][NACC];
        __shared__ double tot[NACC];
        const int k = (int)tid % NACC;
        const int g = (int)tid / NACC;
        if (tid < 8 * NACC) {
            double s = 0.0;
#pragma unroll
            for (int b = 0; b < RBLOCKS / 8; ++b) {
                const int blk = g + b * 8;
                s += __hip_atomic_load(&part[blk * NACC + k],
                                       __ATOMIC_RELAXED, __HIP_MEMORY_SCOPE_AGENT);
            }
            red[g][k] = s;
        }
        __syncthreads();
        if (tid < NACC) {
            double s = 0.0;
#pragma unroll
            for (int g2 = 0; g2 < 8; ++g2) s += red[g2][tid];
            tot[tid] = s;
        }
        __syncthreads();
        if (tid == 0) {
            solve_and_update(tot, ws, pose_in, it, out, write_out);
            atomicExch(counter, 0u);
        }
    }
}

// ---------------------------------------------------------------------------
// Slice-strided mapping: thread handles pixels {tid0 + slot*65536}.
// Consecutive lanes own consecutive pixels -> every gather instruction's lane
// addresses form a ~12B-stride arithmetic sequence (warp ~ identity) ->
// ~12-16 lines/instruction instead of 48-64 with quad ownership. Streams
// are 12B-lane-stride too (line-coalesced; more insts, VALUBusy is 8%).
__global__ __launch_bounds__(RTPB, 1) void icp_fused(
    const float* __restrict__ pose_in,
    const float* __restrict__ vert0, const float* __restrict__ vert1,
    const float* __restrict__ norm0, const float* __restrict__ norm1,
    const float* __restrict__ Kmat, double* __restrict__ ws,
    float* __restrict__ out, int it, int write_out)
{
    // ---- pose: iter0 from input, else from ws (written by prior dispatch) ----
    float R00, R01, R02, t0, R10, R11, R12, t1, R20, R21, R22, t2;
    if (it == 0) {
        R00 = pose_in[0];  R01 = pose_in[1];  R02 = pose_in[2];  t0 = pose_in[3];
        R10 = pose_in[4];  R11 = pose_in[5];  R12 = pose_in[6];  t1 = pose_in[7];
        R20 = pose_in[8];  R21 = pose_in[9];  R22 = pose_in[10]; t2 = pose_in[11];
    } else {
        const double* pose = ws;
        R00 = (float)pose[0];  R01 = (float)pose[1];  R02 = (float)pose[2];  t0 = (float)pose[3];
        R10 = (float)pose[4];  R11 = (float)pose[5];  R12 = (float)pose[6];  t1 = (float)pose[7];
        R20 = (float)pose[8];  R21 = (float)pose[9];  R22 = (float)pose[10]; t2 = (float)pose[11];
    }
    const float fx = Kmat[0], cx = Kmat[2], fy = Kmat[4], cy = Kmat[5];

    float a[NACC];
#pragma unroll
    for (int k = 0; k < NACC; ++k) a[k] = 0.0f;

    // XCD-chunked swizzle (bijective: 256 = 8 XCDs x 32).
    const int sbid = (blockIdx.x & 7) * 32 + (blockIdx.x >> 3);
    const int tid0 = sbid * RTPB + (int)threadIdx.x;

    // current-group stream regs (4 pixel-slots x {vx,vy,vz,nx,ny,nz})
    float cs[4][6];
#pragma unroll
    for (int j = 0; j < 4; ++j) {
        const int pix = tid0 + j * STRIDE;
        const int b = pix * 3;
        cs[j][0] = vert0[b + 0]; cs[j][1] = vert0[b + 1]; cs[j][2] = vert0[b + 2];
        cs[j][3] = norm0[b + 0]; cs[j][4] = norm0[b + 1]; cs[j][5] = norm0[b + 2];
    }

#pragma unroll
    for (int i = 0; i < GROUPS; ++i) {
        // ---- phase A: project 4 slots, compute gather bases ----
        float px[4], py[4], pz[4], nrx[4], nry[4], nrz[4];
        bool inview[4];
        int wb[4];
#pragma unroll
        for (int j = 0; j < 4; ++j) {
            const float vx = cs[j][0], vy = cs[j][1], vz = cs[j][2];
            const float nx = cs[j][3], ny = cs[j][4], nz = cs[j][5];
            px[j] = R00 * vx + R01 * vy + R02 * vz + t0;
            py[j] = R10 * vx + R11 * vy + R12 * vz + t1;
            pz[j] = R20 * vx + R21 * vy + R22 * vz + t2;
            nrx[j] = R00 * nx + R01 * ny + R02 * nz;
            nry[j] = R10 * nx + R11 * ny + R12 * nz;
            nrz[j] = R20 * nx + R21 * ny + R22 * nz;
            const float u = px[j] / pz[j] * fx + cx;
            const float v = py[j] / pz[j] * fy + cy;
            inview[j] = (u > 0.0f) && (u < (float)(W_IMG - 1)) &&
                        (v > 0.0f) && (v < (float)(H_IMG - 1));
            const float uf = fminf(fmaxf(rintf(u), 0.0f), (float)(W_IMG - 1));
            const float vf = fminf(fmaxf(rintf(v), 0.0f), (float)(H_IMG - 1));
            wb[j] = ((int)vf * W_IMG + (int)uf) * 3;
        }

        // ---- phase B: 24 scalar gathers (lane-consecutive addresses) ----
        float r1x[4], r1y[4], r1z[4], m1x[4], m1y[4], m1z[4];
#pragma unroll
        for (int j = 0; j < 4; ++j) {
            r1x[j] = vert1[wb[j]]; r1y[j] = vert1[wb[j] + 1]; r1z[j] = vert1[wb[j] + 2];
            m1x[j] = norm1[wb[j]]; m1y[j] = norm1[wb[j] + 1]; m1z[j] = norm1[wb[j] + 2];
        }

        // ---- prefetch next group's streams (overlaps gather latency) ----
        float ns[4][6];
        if (i + 1 < GROUPS) {
#pragma unroll
            for (int j = 0; j < 4; ++j) {
                const int pix = tid0 + ((i + 1) * 4 + j) * STRIDE;
                const int b = pix * 3;
                ns[j][0] = vert0[b + 0]; ns[j][1] = vert0[b + 1]; ns[j][2] = vert0[b + 2];
                ns[j][3] = norm0[b + 0]; ns[j][4] = norm0[b + 1]; ns[j][5] = norm0[b + 2];
            }
        }

        // ---- phase C: consume, accumulate ----
#pragma unroll
        for (int j = 0; j < 4; ++j) {
            const float dx = px[j] - r1x[j], dy = py[j] - r1y[j], dz = pz[j] - r1z[j];
            const bool mask0 = cs[j][2] > 0.0f;
            const bool mask1 = r1z[j] > 0.0f;
            const bool normal_ok =
                (nrx[j] * m1x[j] + nry[j] * m1y[j] + nrz[j] * m1z[j]) > NORM_THR;
            const float d2 = dx * dx + dy * dy + dz * dz;
            const bool occ = (!inview[j]) || (d2 > DIST_THR2);
            const bool valid = (!occ) && mask0 && mask1 && normal_ok;

            if (valid) {
                const float res = m1x[j] * dx + m1y[j] * dy + m1z[j] * dz;
                float J[6];
                J[0] = py[j] * m1z[j] - pz[j] * m1y[j];
                J[1] = pz[j] * m1x[j] - px[j] * m1z[j];
                J[2] = px[j] * m1y[j] - py[j] * m1x[j];
                J[3] = m1x[j]; J[4] = m1y[j]; J[5] = m1z[j];
                int k = 0;
#pragma unroll
                for (int ii = 0; ii < 6; ++ii)
#pragma unroll
                    for (int jj = ii; jj < 6; ++jj) a[k++] += J[ii] * J[jj];
#pragma unroll
                for (int ii = 0; ii < 6; ++ii) a[21 + ii] += J[ii] * res;
                a[27] += 1.0f;
            }
        }

        if (i + 1 < GROUPS) {
#pragma unroll
            for (int j = 0; j < 4; ++j)
#pragma unroll
                for (int c = 0; c < 6; ++c) cs[j][c] = ns[j][c];
        }
    }

    reduce_and_finish(a, ws, pose_in, it, out, write_out);
}

// ---------------------------------------------------------------------------
extern "C" void kernel_launch(void* const* d_in, const int* in_sizes, int n_in,
                              void* d_out, int out_size, void* d_ws, size_t ws_size,
                              hipStream_t stream) {
    const float* pose10 = (const float*)d_in[0];
    const float* vert0  = (const float*)d_in[1];
    const float* vert1  = (const float*)d_in[2];
    const float* norm0  = (const float*)d_in[3];
    const float* norm1  = (const float*)d_in[4];
    const float* Kmat   = (const float*)d_in[5];
    float* out = (float*)d_out;
    double* ws = (double*)d_ws;

    icp_init0<<<1, 64, 0, stream>>>(ws);
    for (int it = 0; it < 3; ++it) {
        icp_fused<<<RBLOCKS, RTPB, 0, stream>>>(pose10, vert0, vert1, norm0, norm1,
                                                Kmat, ws, out, it, it == 2 ? 1 : 0);
    }
}